// Round 10
// baseline (572.365 us; speedup 1.0000x reference)
//
#include <hip/hip_runtime.h>

#define DD 128
#define ADJ_CAP 1024

typedef __attribute__((ext_vector_type(8))) short short8;
typedef __attribute__((ext_vector_type(4))) float f32x4;

__device__ inline unsigned short f2bf(float f) {
    unsigned u = __float_as_uint(f);
    unsigned r = (u + 0x7fffu + ((u >> 16) & 1u)) >> 16;
    return (unsigned short)r;
}
__device__ inline float bf2f(unsigned short u) {
    return __uint_as_float(((unsigned)u) << 16);
}
__device__ inline float bflo(unsigned u) { return __uint_as_float(u << 16); }
__device__ inline float bfhi(unsigned u) { return __uint_as_float(u & 0xffff0000u); }
__device__ inline unsigned pack2(float a, float b) {
    return (unsigned)f2bf(a) | ((unsigned)f2bf(b) << 16);
}

// ---------------- fp32 -> bf16 convert ----------------
__global__ __launch_bounds__(256) void conv_all(const float* __restrict__ inA, unsigned short* __restrict__ outA, int n4A,
                                                const float* __restrict__ inP, unsigned short* __restrict__ outP, int n4P) {
    int i = blockIdx.x * blockDim.x + threadIdx.x;
    const float* in;
    unsigned short* out;
    int j;
    if (i < n4A) { in = inA; out = outA; j = i; }
    else if (i < n4A + n4P) { in = inP; out = outP; j = i - n4A; }
    else return;
    float4 v = *(const float4*)(in + (size_t)j * 4);
    uint2 o;
    o.x = pack2(v.x, v.y);
    o.y = pack2(v.z, v.w);
    *(uint2*)(out + (size_t)j * 4) = o;
}

// ---------------- weight pack ----------------
__global__ __launch_bounds__(256) void pack_all(const float* __restrict__ Wa2p, const float* __restrict__ Wpself,
                                                const float* __restrict__ Wp2a, const float* __restrict__ Waself,
                                                const float* __restrict__ Wco,
                                                short* __restrict__ BPp0, short* __restrict__ BPp1,
                                                short* __restrict__ BPa0, short* __restrict__ BPa1,
                                                short* __restrict__ BPc0, short* __restrict__ BPc1) {
    const int WL = 128 * 128;
    int idx = blockIdx.x * blockDim.x + threadIdx.x;
    int seg = idx >> 12;
    int sidx = idx & 4095;
    const float *W1, *W2;
    short* dst;
    int ktiles;
    switch (seg) {
        case 0: W1 = Wa2p;      W2 = Wpself;      dst = BPp0; ktiles = 8; break;
        case 1: W1 = Wa2p + WL; W2 = Wpself + WL; dst = BPp1; ktiles = 8; break;
        case 2: W1 = Wp2a;      W2 = Waself;      dst = BPa0; ktiles = 8; break;
        case 3: W1 = Wp2a + WL; W2 = Waself + WL; dst = BPa1; ktiles = 8; break;
        case 4: W1 = Wco;       W2 = nullptr;     dst = BPc0; ktiles = 4; break;
        default: W1 = Wco + WL; W2 = nullptr;     dst = BPc1; ktiles = 4; break;
    }
    int total = 8 * ktiles * 64;
    if (sidx >= total) return;
    int lane = sidx & 63;
    int kk = (sidx >> 6) % ktiles;
    int t = (sidx >> 6) / ktiles;
    int n = t * 16 + (lane & 15);
    int kbase = kk * 32 + (lane >> 4) * 8;
    short8 v;
#pragma unroll
    for (int j = 0; j < 8; ++j) {
        int k = kbase + j;
        float f = (k < 128) ? W1[n * 128 + k] : W2[n * 128 + (k - 128)];
        v[j] = (short)f2bf(f);
    }
    *(short8*)(dst + (size_t)sidx * 8) = v;
}

// ---------------- CSR build ----------------
__global__ __launch_bounds__(256) void count_all(const int* __restrict__ aidx, const int* __restrict__ pidx,
                                                 const int* __restrict__ cod,
                                                 int* __restrict__ cntP, int* __restrict__ cntA,
                                                 int* __restrict__ cntC, int E, int Eco) {
    int i = blockIdx.x * blockDim.x + threadIdx.x;
    if (i < E) {
        atomicAdd(&cntP[pidx[i]], 1);
        atomicAdd(&cntA[aidx[i]], 1);
    } else if (i < E + Eco) {
        atomicAdd(&cntC[cod[i - E]], 1);
    }
}

__global__ __launch_bounds__(256) void scan_local3(const int* __restrict__ c0, int* __restrict__ r0, int* __restrict__ p0, int N0,
                                                   const int* __restrict__ c1, int* __restrict__ r1, int* __restrict__ p1, int N1,
                                                   const int* __restrict__ c2, int* __restrict__ r2, int* __restrict__ p2, int N2,
                                                   int nb0, int nb1) {
    __shared__ int sh[256];
    int b = blockIdx.x;
    const int* cnt; int* row; int* partials; int N; int lb;
    if (b < nb0) { cnt = c0; row = r0; partials = p0; N = N0; lb = b; }
    else if (b < nb0 + nb1) { cnt = c1; row = r1; partials = p1; N = N1; lb = b - nb0; }
    else { cnt = c2; row = r2; partials = p2; N = N2; lb = b - nb0 - nb1; }
    int t = threadIdx.x;
    int base = lb * 1024 + t * 4;
    int v0 = 0, v1 = 0, v2 = 0, v3 = 0;
    if (base + 0 < N) v0 = cnt[base + 0];
    if (base + 1 < N) v1 = cnt[base + 1];
    if (base + 2 < N) v2 = cnt[base + 2];
    if (base + 3 < N) v3 = cnt[base + 3];
    sh[t] = v0 + v1 + v2 + v3;
    __syncthreads();
    for (int off = 1; off < 256; off <<= 1) {
        int y = (t >= off) ? sh[t - off] : 0;
        __syncthreads();
        sh[t] += y;
        __syncthreads();
    }
    int excl = (t > 0) ? sh[t - 1] : 0;
    if (t == 255) partials[lb] = sh[255];
    if (base + 0 < N) row[base + 0] = excl; excl += v0;
    if (base + 1 < N) row[base + 1] = excl; excl += v1;
    if (base + 2 < N) row[base + 2] = excl; excl += v2;
    if (base + 3 < N) row[base + 3] = excl;
}

__global__ __launch_bounds__(256) void scan_partials3(int* __restrict__ p0, int nb0,
                                                      int* __restrict__ p1, int nb1,
                                                      int* __restrict__ p2, int nb2) {
    __shared__ int sh[256];
    int* partials; int nb;
    if (blockIdx.x == 0) { partials = p0; nb = nb0; }
    else if (blockIdx.x == 1) { partials = p1; nb = nb1; }
    else { partials = p2; nb = nb2; }
    int t = threadIdx.x;
    int v = (t < nb) ? partials[t] : 0;
    sh[t] = v;
    __syncthreads();
    for (int off = 1; off < 256; off <<= 1) {
        int y = (t >= off) ? sh[t - off] : 0;
        __syncthreads();
        sh[t] += y;
        __syncthreads();
    }
    if (t < nb) partials[t] = (t > 0) ? sh[t - 1] : 0;
}

__global__ __launch_bounds__(256) void scan_finalize3(int* __restrict__ r0, int* __restrict__ cu0, const int* __restrict__ p0, int N0,
                                                      int* __restrict__ r1, int* __restrict__ cu1, const int* __restrict__ p1, int N1,
                                                      int* __restrict__ r2, int* __restrict__ cu2, const int* __restrict__ p2, int N2,
                                                      int fb0, int fb1) {
    int b = blockIdx.x;
    int* row; int* cur; const int* partials; int N; int lb;
    if (b < fb0) { row = r0; cur = cu0; partials = p0; N = N0; lb = b; }
    else if (b < fb0 + fb1) { row = r1; cur = cu1; partials = p1; N = N1; lb = b - fb0; }
    else { row = r2; cur = cu2; partials = p2; N = N2; lb = b - fb0 - fb1; }
    int i = lb * 256 + threadIdx.x;
    if (i >= N) return;
    int r = row[i] + partials[i >> 10];
    row[i] = r;
    cur[i] = r;
}

__global__ __launch_bounds__(256) void fill_all(const int* __restrict__ aidx, const int* __restrict__ pidx,
                                                const int* __restrict__ cos_, const int* __restrict__ cod,
                                                int* __restrict__ curP, int* __restrict__ curA, int* __restrict__ curC,
                                                int* __restrict__ adjP, int* __restrict__ adjA, int* __restrict__ adjC,
                                                int E, int Eco) {
    int i = blockIdx.x * blockDim.x + threadIdx.x;
    if (i < E) {
        int a = aidx[i], pp = pidx[i];
        adjP[atomicAdd(&curP[pp], 1)] = a;
        adjA[atomicAdd(&curA[a], 1)] = pp;
    } else if (i < E + Eco) {
        adjC[atomicAdd(&curC[cod[i - E]], 1)] = cos_[i - E];
    }
}

// ---------------- fused: chunk-2 register gather + LDS adj + LDS agg/self + MFMA ----------------
struct FParams {
    const unsigned short* gsrc;
    const unsigned short* selfx;
    const unsigned short* base;
    const int* adj;
    const int* rowp;
    const int* cnt;
    const short* Bpack;
    const float* b1;
    const float* b2;
    unsigned short* out;
    int M;
};

template <int KTILES, bool HAS_B2, bool ADD_BASE>
__device__ __forceinline__ void fused_body(char* lds, int* ldsAdj, const FParams& p, int blk) {
    constexpr int STRB = KTILES * 64;   // 512 (dual) / 256 (co) bytes per LDS row
    const int tid = threadIdx.x;
    const int node0 = blk * 64;
    const int grp = tid >> 4;   // 16 groups of 16 lanes
    const int l = tid & 15;     // 16B slice within a 256B row

    // stage block adjacency into LDS (coalesced)
    const int lastNode = (node0 + 63 < p.M) ? node0 + 63 : p.M - 1;
    const int est = p.rowp[node0];
    const int eend = p.rowp[lastNode] + p.cnt[lastNode];
    const int nE = eend - est;
    for (int j = tid; j < nE && j < ADJ_CAP; j += 256) ldsAdj[j] = p.adj[est + j];

    // prefetch self rows coalesced (4 rows/group, 16B/lane) — overlaps gather latency
    uint4 selfv[4];
    if (KTILES == 8) {
#pragma unroll
        for (int i = 0; i < 4; ++i) {
            int node = node0 + grp * 4 + i;
            if (node >= p.M) node = p.M - 1;
            selfv[i] = *(const uint4*)(p.selfx + (size_t)node * DD + l * 8);
        }
    }

    // row metadata
    int relSt[4], dA[4];
#pragma unroll
    for (int i = 0; i < 4; ++i) {
        int node = node0 + grp * 4 + i;
        bool ok = node < p.M;
        relSt[i] = ok ? (p.rowp[node] - est) : 0;
        dA[i] = ok ? p.cnt[node] : 0;
    }
    __syncthreads();

    float acc[4][8];
#pragma unroll
    for (int i = 0; i < 4; ++i)
#pragma unroll
        for (int j = 0; j < 8; ++j) acc[i][j] = 0.f;

    int dmax = dA[0];
#pragma unroll
    for (int i = 1; i < 4; ++i) dmax = dA[i] > dmax ? dA[i] : dmax;

    // chunk-2 gather (8 independent uint4 loads per iteration across 4 rows)
    auto gather = [&](auto idxAt) {
        for (int k = 0; k < dmax; k += 2) {
#pragma unroll
            for (int i = 0; i < 4; ++i) {
                if (k < dA[i]) {
                    int rem = dA[i] - k;
                    int o0 = relSt[i] + k;
                    int s0 = idxAt(o0);
                    int s1 = idxAt(o0 + ((rem > 1) ? 1 : 0));
                    float w1 = (rem > 1) ? 1.f : 0.f;
                    uint4 v0 = *(const uint4*)(p.gsrc + (size_t)s0 * DD + l * 8);
                    uint4 v1 = *(const uint4*)(p.gsrc + (size_t)s1 * DD + l * 8);
                    acc[i][0] += bflo(v0.x); acc[i][1] += bfhi(v0.x);
                    acc[i][2] += bflo(v0.y); acc[i][3] += bfhi(v0.y);
                    acc[i][4] += bflo(v0.z); acc[i][5] += bfhi(v0.z);
                    acc[i][6] += bflo(v0.w); acc[i][7] += bfhi(v0.w);
                    acc[i][0] += w1 * bflo(v1.x); acc[i][1] += w1 * bfhi(v1.x);
                    acc[i][2] += w1 * bflo(v1.y); acc[i][3] += w1 * bfhi(v1.y);
                    acc[i][4] += w1 * bflo(v1.z); acc[i][5] += w1 * bfhi(v1.z);
                    acc[i][6] += w1 * bflo(v1.w); acc[i][7] += w1 * bfhi(v1.w);
                }
            }
        }
    };
    if (nE <= ADJ_CAP) gather([&](int o) { return ldsAdj[o]; });
    else               gather([&](int o) { return p.adj[est + o]; });

    // write agg tile (bf16, swizzled) + self tile
#pragma unroll
    for (int i = 0; i < 4; ++i) {
        int lr = grp * 4 + i;
        uint4 o = make_uint4(pack2(acc[i][0], acc[i][1]), pack2(acc[i][2], acc[i][3]),
                             pack2(acc[i][4], acc[i][5]), pack2(acc[i][6], acc[i][7]));
        int colb = l * 16;
        *(uint4*)(lds + lr * STRB + (colb ^ ((lr & 7) << 4))) = o;
    }
    if (KTILES == 8) {
#pragma unroll
        for (int i = 0; i < 4; ++i) {
            int lr = grp * 4 + i;
            int colb = 256 + l * 16;
            *(uint4*)(lds + lr * STRB + (colb ^ ((lr & 7) << 4))) = selfv[i];
        }
    }
    __syncthreads();

    // MFMA phase: all K tiles from LDS
    const int wave = tid >> 6;
    const int lane = tid & 63;
    const int kg = lane >> 4;
    const int lrA = wave * 16 + (lane & 15);

    f32x4 facc[8];
#pragma unroll
    for (int t = 0; t < 8; ++t) facc[t] = (f32x4){0.f, 0.f, 0.f, 0.f};

#pragma unroll
    for (int kk = 0; kk < KTILES; ++kk) {
        int colb = kk * 64 + kg * 16;
        short8 af = *(const short8*)(lds + lrA * STRB + (colb ^ ((lrA & 7) << 4)));
#pragma unroll
        for (int t = 0; t < 8; ++t) {
            short8 bf = *(const short8*)(p.Bpack + ((size_t)(t * KTILES + kk) * 64 + lane) * 8);
            facc[t] = __builtin_amdgcn_mfma_f32_16x16x32_bf16(af, bf, facc[t], 0, 0, 0);
        }
    }

    // epilogue
    const int col0 = lane & 15;
    const int crow0 = node0 + wave * 16 + kg * 4;
#pragma unroll
    for (int t = 0; t < 8; ++t) {
        int col = t * 16 + col0;
        float bb = p.b1[col];
        float b2v = HAS_B2 ? p.b2[col] : 0.f;
#pragma unroll
        for (int r = 0; r < 4; ++r) {
            int row = crow0 + r;
            if (row < p.M) {
                float v = facc[t][r] + (float)p.cnt[row] * bb + b2v;
                if (ADD_BASE) v += bf2f(p.base[(size_t)row * DD + col]);
                p.out[(size_t)row * DD + col] = f2bf(v);
            }
        }
    }
}

__global__ __launch_bounds__(256, 4) void fused_dual_kernel(FParams pP, FParams pA, int blkP) {
    __shared__ char lds[32768];
    __shared__ int ldsAdj[ADJ_CAP];
    bool isP = (int)blockIdx.x < blkP;
    const FParams& p = isP ? pP : pA;
    fused_body<8, true, false>(lds, ldsAdj, p, isP ? blockIdx.x : blockIdx.x - blkP);
}

__global__ __launch_bounds__(256, 6) void fused_co_kernel(FParams p) {
    __shared__ char lds[16384];
    __shared__ int ldsAdj[ADJ_CAP];
    fused_body<4, false, true>(lds, ldsAdj, p, blockIdx.x);
}

// ---------------- supervision dot ----------------
__global__ __launch_bounds__(256) void dot_kernel(
    const unsigned short* __restrict__ xa, const unsigned short* __restrict__ xp,
    const int* __restrict__ s0, const int* __restrict__ s1,
    float* __restrict__ out, int E) {
    int g = blockIdx.x * blockDim.x + threadIdx.x;
    int e = g >> 4;
    int l = g & 15;
    if (e >= E) return;
    int a = s0[e], p = s1[e];
    uint4 va = *(const uint4*)(xa + (size_t)a * DD + l * 8);
    uint4 vp = *(const uint4*)(xp + (size_t)p * DD + l * 8);
    float s = bflo(va.x) * bflo(vp.x) + bfhi(va.x) * bfhi(vp.x)
            + bflo(va.y) * bflo(vp.y) + bfhi(va.y) * bfhi(vp.y)
            + bflo(va.z) * bflo(vp.z) + bfhi(va.z) * bfhi(vp.z)
            + bflo(va.w) * bflo(vp.w) + bfhi(va.w) * bfhi(vp.w);
    s += __shfl_xor(s, 1); s += __shfl_xor(s, 2);
    s += __shfl_xor(s, 4); s += __shfl_xor(s, 8);
    if (l == 0) out[e] = s;
}

extern "C" void kernel_launch(void* const* d_in, const int* in_sizes, int n_in,
                              void* d_out, int out_size, void* d_ws, size_t ws_size,
                              hipStream_t stream) {
    const float* xa_in = (const float*)d_in[0];
    const float* xp_in = (const float*)d_in[1];
    const int* eidx = (const int*)d_in[2];
    const int* co = (const int*)d_in[3];
    const int* sup = (const int*)d_in[4];
    const float* W_a2p = (const float*)d_in[5];
    const float* b_a2p = (const float*)d_in[6];
    const float* W_p2a = (const float*)d_in[7];
    const float* b_p2a = (const float*)d_in[8];
    const float* W_aself = (const float*)d_in[9];
    const float* b_aself = (const float*)d_in[10];
    const float* W_pself = (const float*)d_in[11];
    const float* b_pself = (const float*)d_in[12];
    const float* W_co = (const float*)d_in[13];
    const float* b_co = (const float*)d_in[14];

    const int NA = in_sizes[0] / DD;
    const int NP = in_sizes[1] / DD;
    const int E = in_sizes[2] / 2;
    const int Eco = in_sizes[3] / 2;
    const int Esup = in_sizes[4] / 2;
    const int* a_idx = eidx;
    const int* p_idx = eidx + E;
    const int* co_s = co;
    const int* co_d = co + Eco;
    const int* s0 = sup;
    const int* s1 = sup + Esup;

    char* w = (char*)d_ws;
    auto carve = [&](size_t bytes) -> char* {
        char* p = w;
        w += (bytes + 255) & ~(size_t)255;
        return p;
    };
    unsigned short* XA = (unsigned short*)carve((size_t)NA * DD * 2);
    unsigned short* XP = (unsigned short*)carve((size_t)NP * DD * 2);
    unsigned short* P0b = (unsigned short*)carve((size_t)NP * DD * 2);
    unsigned short* P1b = (unsigned short*)carve((size_t)NP * DD * 2);
    unsigned short* A0b = (unsigned short*)carve((size_t)NA * DD * 2);
    unsigned short* A1b = (unsigned short*)carve((size_t)NA * DD * 2);
    int* cntP = (int*)carve((size_t)NP * 4);
    int* cntA = (int*)carve((size_t)NA * 4);
    int* cntC = (int*)carve((size_t)NA * 4);
    size_t cntSpan = (size_t)((char*)cntC - (char*)cntP) + (((size_t)NA * 4 + 255) & ~(size_t)255);
    int* rowP = (int*)carve((size_t)NP * 4);
    int* curP = (int*)carve((size_t)NP * 4);
    int* rowA = (int*)carve((size_t)NA * 4);
    int* curA = (int*)carve((size_t)NA * 4);
    int* rowC = (int*)carve((size_t)NA * 4);
    int* curC = (int*)carve((size_t)NA * 4);
    int* adjP = (int*)carve((size_t)E * 4);
    int* adjA = (int*)carve((size_t)E * 4);
    int* adjC = (int*)carve((size_t)Eco * 4);
    int* partP = (int*)carve(256 * 4);
    int* partA = (int*)carve(256 * 4);
    int* partC = (int*)carve(256 * 4);
    short* BPp0 = (short*)carve(8 * 8 * 64 * 8 * 2);
    short* BPp1 = (short*)carve(8 * 8 * 64 * 8 * 2);
    short* BPa0 = (short*)carve(8 * 8 * 64 * 8 * 2);
    short* BPa1 = (short*)carve(8 * 8 * 64 * 8 * 2);
    short* BPc0 = (short*)carve(8 * 4 * 64 * 8 * 2);
    short* BPc1 = (short*)carve(8 * 4 * 64 * 8 * 2);

    int n4A = NA * DD / 4, n4P = NP * DD / 4;
    conv_all<<<(n4A + n4P + 255) / 256, 256, 0, stream>>>(xa_in, XA, n4A, xp_in, XP, n4P);
    pack_all<<<96, 256, 0, stream>>>(W_a2p, W_pself, W_p2a, W_aself, W_co, BPp0, BPp1, BPa0, BPa1, BPc0, BPc1);

    hipMemsetAsync(cntP, 0, cntSpan, stream);
    count_all<<<(E + Eco + 255) / 256, 256, 0, stream>>>(a_idx, p_idx, co_d, cntP, cntA, cntC, E, Eco);
    const int nbP = (NP + 1023) / 1024;
    const int nbA = (NA + 1023) / 1024;
    scan_local3<<<nbP + nbA + nbA, 256, 0, stream>>>(cntP, rowP, partP, NP, cntA, rowA, partA, NA, cntC, rowC, partC, NA, nbP, nbA);
    scan_partials3<<<3, 256, 0, stream>>>(partP, nbP, partA, nbA, partC, nbA);
    const int fbP = (NP + 255) / 256;
    const int fbA = (NA + 255) / 256;
    scan_finalize3<<<fbP + fbA + fbA, 256, 0, stream>>>(rowP, curP, partP, NP, rowA, curA, partA, NA, rowC, curC, partC, NA, fbP, fbA);
    fill_all<<<(E + Eco + 255) / 256, 256, 0, stream>>>(a_idx, p_idx, co_s, co_d, curP, curA, curC, adjP, adjA, adjC, E, Eco);

    const int blkP = (NP + 63) / 64;
    const int blkA = (NA + 63) / 64;

    FParams pP1 = {XA, XP, nullptr, adjP, rowP, cntP, BPp0, b_a2p, b_pself, P0b, NP};
    FParams pA1 = {XP, XA, nullptr, adjA, rowA, cntA, BPa0, b_p2a, b_aself, A0b, NA};
    FParams pC1 = {A0b, nullptr, A0b, adjC, rowC, cntC, BPc0, b_co, nullptr, A1b, NA};
    FParams pP2 = {A1b, P0b, nullptr, adjP, rowP, cntP, BPp1, b_a2p + 128, b_pself + 128, P1b, NP};
    FParams pA2 = {P0b, A1b, nullptr, adjA, rowA, cntA, BPa1, b_p2a + 128, b_aself + 128, A0b, NA};
    FParams pC2 = {A0b, nullptr, A0b, adjC, rowC, cntC, BPc1, b_co + 128, nullptr, A1b, NA};

    // Layer 1
    fused_dual_kernel<<<blkP + blkA, 256, 0, stream>>>(pP1, pA1, blkP);
    fused_co_kernel<<<blkA, 256, 0, stream>>>(pC1);
    // Layer 2
    fused_dual_kernel<<<blkP + blkA, 256, 0, stream>>>(pP2, pA2, blkP);
    fused_co_kernel<<<blkA, 256, 0, stream>>>(pC2);

    // output
    dot_kernel<<<(Esup * 16 + 255) / 256, 256, 0, stream>>>(A1b, P1b, s0, s1, (float*)d_out, Esup);
}

// Round 11
// 500.906 us; speedup vs baseline: 1.1427x; 1.1427x over previous
//
#include <hip/hip_runtime.h>

#define DD 128
#define ADJ_CAP 1024

typedef __attribute__((ext_vector_type(8))) short short8;
typedef __attribute__((ext_vector_type(16))) float f32x16;

__device__ inline unsigned short f2bf(float f) {
    unsigned u = __float_as_uint(f);
    unsigned r = (u + 0x7fffu + ((u >> 16) & 1u)) >> 16;
    return (unsigned short)r;
}
__device__ inline float bf2f(unsigned short u) {
    return __uint_as_float(((unsigned)u) << 16);
}
__device__ inline float bflo(unsigned u) { return __uint_as_float(u << 16); }
__device__ inline float bfhi(unsigned u) { return __uint_as_float(u & 0xffff0000u); }
__device__ inline unsigned pack2(float a, float b) {
    return (unsigned)f2bf(a) | ((unsigned)f2bf(b) << 16);
}

// ---------------- fp32 -> bf16 convert ----------------
__global__ __launch_bounds__(256) void conv_all(const float* __restrict__ inA, unsigned short* __restrict__ outA, int n4A,
                                                const float* __restrict__ inP, unsigned short* __restrict__ outP, int n4P) {
    int i = blockIdx.x * blockDim.x + threadIdx.x;
    const float* in;
    unsigned short* out;
    int j;
    if (i < n4A) { in = inA; out = outA; j = i; }
    else if (i < n4A + n4P) { in = inP; out = outP; j = i - n4A; }
    else return;
    float4 v = *(const float4*)(in + (size_t)j * 4);
    uint2 o;
    o.x = pack2(v.x, v.y);
    o.y = pack2(v.z, v.w);
    *(uint2*)(out + (size_t)j * 4) = o;
}

// ---------------- weight pack for mfma_f32_32x32x16_bf16 ----------------
// Bpack[((ct*KS + ks)*64 + lane)*8 + j] = Wcat[n][k], n = ct*32 + (lane&31),
// k = ks*16 + (lane>>5)*8 + j.  Wcat = [W1 | W2] along k (k>=128 -> W2).
__global__ __launch_bounds__(256) void pack_all(const float* __restrict__ Wa2p, const float* __restrict__ Wpself,
                                                const float* __restrict__ Wp2a, const float* __restrict__ Waself,
                                                const float* __restrict__ Wco,
                                                short* __restrict__ BPp0, short* __restrict__ BPp1,
                                                short* __restrict__ BPa0, short* __restrict__ BPa1,
                                                short* __restrict__ BPc0, short* __restrict__ BPc1) {
    const int WL = 128 * 128;
    int idx = blockIdx.x * blockDim.x + threadIdx.x;
    int seg = idx >> 12;
    int sidx = idx & 4095;
    const float *W1, *W2;
    short* dst;
    int KS;
    switch (seg) {
        case 0: W1 = Wa2p;      W2 = Wpself;      dst = BPp0; KS = 16; break;
        case 1: W1 = Wa2p + WL; W2 = Wpself + WL; dst = BPp1; KS = 16; break;
        case 2: W1 = Wp2a;      W2 = Waself;      dst = BPa0; KS = 16; break;
        case 3: W1 = Wp2a + WL; W2 = Waself + WL; dst = BPa1; KS = 16; break;
        case 4: W1 = Wco;       W2 = nullptr;     dst = BPc0; KS = 8; break;
        default: W1 = Wco + WL; W2 = nullptr;     dst = BPc1; KS = 8; break;
    }
    int total = 4 * KS * 64;
    if (sidx >= total) return;
    int lane = sidx & 63;
    int rest = sidx >> 6;
    int ks = rest % KS;
    int ct = rest / KS;
    int n = ct * 32 + (lane & 31);
    int kbase = ks * 16 + (lane >> 5) * 8;
    short8 v;
#pragma unroll
    for (int j = 0; j < 8; ++j) {
        int k = kbase + j;
        float f = (k < 128) ? W1[n * 128 + k] : W2[n * 128 + (k - 128)];
        v[j] = (short)f2bf(f);
    }
    *(short8*)(dst + (size_t)sidx * 8) = v;
}

// ---------------- CSR build ----------------
__global__ __launch_bounds__(256) void count_all(const int* __restrict__ aidx, const int* __restrict__ pidx,
                                                 const int* __restrict__ cod,
                                                 int* __restrict__ cntP, int* __restrict__ cntA,
                                                 int* __restrict__ cntC, int E, int Eco) {
    int i = blockIdx.x * blockDim.x + threadIdx.x;
    if (i < E) {
        atomicAdd(&cntP[pidx[i]], 1);
        atomicAdd(&cntA[aidx[i]], 1);
    } else if (i < E + Eco) {
        atomicAdd(&cntC[cod[i - E]], 1);
    }
}

__global__ __launch_bounds__(256) void scan_local3(const int* __restrict__ c0, int* __restrict__ r0, int* __restrict__ p0, int N0,
                                                   const int* __restrict__ c1, int* __restrict__ r1, int* __restrict__ p1, int N1,
                                                   const int* __restrict__ c2, int* __restrict__ r2, int* __restrict__ p2, int N2,
                                                   int nb0, int nb1) {
    __shared__ int sh[256];
    int b = blockIdx.x;
    const int* cnt; int* row; int* partials; int N; int lb;
    if (b < nb0) { cnt = c0; row = r0; partials = p0; N = N0; lb = b; }
    else if (b < nb0 + nb1) { cnt = c1; row = r1; partials = p1; N = N1; lb = b - nb0; }
    else { cnt = c2; row = r2; partials = p2; N = N2; lb = b - nb0 - nb1; }
    int t = threadIdx.x;
    int base = lb * 1024 + t * 4;
    int v0 = 0, v1 = 0, v2 = 0, v3 = 0;
    if (base + 0 < N) v0 = cnt[base + 0];
    if (base + 1 < N) v1 = cnt[base + 1];
    if (base + 2 < N) v2 = cnt[base + 2];
    if (base + 3 < N) v3 = cnt[base + 3];
    sh[t] = v0 + v1 + v2 + v3;
    __syncthreads();
    for (int off = 1; off < 256; off <<= 1) {
        int y = (t >= off) ? sh[t - off] : 0;
        __syncthreads();
        sh[t] += y;
        __syncthreads();
    }
    int excl = (t > 0) ? sh[t - 1] : 0;
    if (t == 255) partials[lb] = sh[255];
    if (base + 0 < N) row[base + 0] = excl; excl += v0;
    if (base + 1 < N) row[base + 1] = excl; excl += v1;
    if (base + 2 < N) row[base + 2] = excl; excl += v2;
    if (base + 3 < N) row[base + 3] = excl;
}

__global__ __launch_bounds__(256) void scan_partials3(int* __restrict__ p0, int nb0,
                                                      int* __restrict__ p1, int nb1,
                                                      int* __restrict__ p2, int nb2) {
    __shared__ int sh[256];
    int* partials; int nb;
    if (blockIdx.x == 0) { partials = p0; nb = nb0; }
    else if (blockIdx.x == 1) { partials = p1; nb = nb1; }
    else { partials = p2; nb = nb2; }
    int t = threadIdx.x;
    int v = (t < nb) ? partials[t] : 0;
    sh[t] = v;
    __syncthreads();
    for (int off = 1; off < 256; off <<= 1) {
        int y = (t >= off) ? sh[t - off] : 0;
        __syncthreads();
        sh[t] += y;
        __syncthreads();
    }
    if (t < nb) partials[t] = (t > 0) ? sh[t - 1] : 0;
}

__global__ __launch_bounds__(256) void scan_finalize3(int* __restrict__ r0, int* __restrict__ cu0, const int* __restrict__ p0, int N0,
                                                      int* __restrict__ r1, int* __restrict__ cu1, const int* __restrict__ p1, int N1,
                                                      int* __restrict__ r2, int* __restrict__ cu2, const int* __restrict__ p2, int N2,
                                                      int fb0, int fb1) {
    int b = blockIdx.x;
    int* row; int* cur; const int* partials; int N; int lb;
    if (b < fb0) { row = r0; cur = cu0; partials = p0; N = N0; lb = b; }
    else if (b < fb0 + fb1) { row = r1; cur = cu1; partials = p1; N = N1; lb = b - fb0; }
    else { row = r2; cur = cu2; partials = p2; N = N2; lb = b - fb0 - fb1; }
    int i = lb * 256 + threadIdx.x;
    if (i >= N) return;
    int r = row[i] + partials[i >> 10];
    row[i] = r;
    cur[i] = r;
}

__global__ __launch_bounds__(256) void fill_all(const int* __restrict__ aidx, const int* __restrict__ pidx,
                                                const int* __restrict__ cos_, const int* __restrict__ cod,
                                                int* __restrict__ curP, int* __restrict__ curA, int* __restrict__ curC,
                                                int* __restrict__ adjP, int* __restrict__ adjA, int* __restrict__ adjC,
                                                int E, int Eco) {
    int i = blockIdx.x * blockDim.x + threadIdx.x;
    if (i < E) {
        int a = aidx[i], pp = pidx[i];
        adjP[atomicAdd(&curP[pp], 1)] = a;
        adjA[atomicAdd(&curA[a], 1)] = pp;
    } else if (i < E + Eco) {
        adjC[atomicAdd(&curC[cod[i - E]], 1)] = cos_[i - E];
    }
}

// ---------------- fused: chunk-4 register gather + LDS adj + 32x32 MFMA ----------------
struct FParams {
    const unsigned short* gsrc;
    const unsigned short* selfx;
    const unsigned short* base;
    const int* adj;
    const int* rowp;
    const int* cnt;
    const short* Bpack;
    const float* b1;
    const float* b2;
    unsigned short* out;
    int M;
};

template <int KS, bool HAS_B2, bool ADD_BASE>
__device__ __forceinline__ void fused_body(char* lds, int* ldsAdj, const FParams& p, int blk) {
    const int tid = threadIdx.x;
    const int node0 = blk * 64;
    const int grp = tid >> 4;   // 16 groups of 16 lanes
    const int l = tid & 15;     // 16B slice within a 256B row

    // stage block adjacency into LDS (coalesced)
    const int lastNode = (node0 + 63 < p.M) ? node0 + 63 : p.M - 1;
    const int est = p.rowp[node0];
    const int eend = p.rowp[lastNode] + p.cnt[lastNode];
    const int nE = eend - est;
    for (int j = tid; j < nE && j < ADJ_CAP; j += 256) ldsAdj[j] = p.adj[est + j];

    // row metadata
    int relSt[4], dA[4];
#pragma unroll
    for (int i = 0; i < 4; ++i) {
        int node = node0 + grp * 4 + i;
        bool ok = node < p.M;
        relSt[i] = ok ? (p.rowp[node] - est) : 0;
        dA[i] = ok ? p.cnt[node] : 0;
    }
    __syncthreads();

    float acc[4][8];
#pragma unroll
    for (int i = 0; i < 4; ++i)
#pragma unroll
        for (int j = 0; j < 8; ++j) acc[i][j] = 0.f;

    int dmax = dA[0];
#pragma unroll
    for (int i = 1; i < 4; ++i) dmax = dA[i] > dmax ? dA[i] : dmax;

    // chunk-4 gather (16 independent uint4 loads in flight per group)
    auto gather = [&](auto idxAt) {
        for (int k = 0; k < dmax; k += 4) {
#pragma unroll
            for (int i = 0; i < 4; ++i) {
                if (k < dA[i]) {
                    int rem = dA[i] - k;
                    int o0 = relSt[i] + k;
                    int s0 = idxAt(o0);
                    int s1 = idxAt(o0 + ((rem > 1) ? 1 : 0));
                    int s2 = idxAt(o0 + ((rem > 2) ? 2 : 0));
                    int s3 = idxAt(o0 + ((rem > 3) ? 3 : 0));
                    float w1 = (rem > 1) ? 1.f : 0.f;
                    float w2 = (rem > 2) ? 1.f : 0.f;
                    float w3 = (rem > 3) ? 1.f : 0.f;
                    uint4 v0 = *(const uint4*)(p.gsrc + (size_t)s0 * DD + l * 8);
                    uint4 v1 = *(const uint4*)(p.gsrc + (size_t)s1 * DD + l * 8);
                    uint4 v2 = *(const uint4*)(p.gsrc + (size_t)s2 * DD + l * 8);
                    uint4 v3 = *(const uint4*)(p.gsrc + (size_t)s3 * DD + l * 8);
                    acc[i][0] += bflo(v0.x); acc[i][1] += bfhi(v0.x);
                    acc[i][2] += bflo(v0.y); acc[i][3] += bfhi(v0.y);
                    acc[i][4] += bflo(v0.z); acc[i][5] += bfhi(v0.z);
                    acc[i][6] += bflo(v0.w); acc[i][7] += bfhi(v0.w);
                    acc[i][0] += w1 * bflo(v1.x); acc[i][1] += w1 * bfhi(v1.x);
                    acc[i][2] += w1 * bflo(v1.y); acc[i][3] += w1 * bfhi(v1.y);
                    acc[i][4] += w1 * bflo(v1.z); acc[i][5] += w1 * bfhi(v1.z);
                    acc[i][6] += w1 * bflo(v1.w); acc[i][7] += w1 * bfhi(v1.w);
                    acc[i][0] += w2 * bflo(v2.x); acc[i][1] += w2 * bfhi(v2.x);
                    acc[i][2] += w2 * bflo(v2.y); acc[i][3] += w2 * bfhi(v2.y);
                    acc[i][4] += w2 * bflo(v2.z); acc[i][5] += w2 * bfhi(v2.z);
                    acc[i][6] += w2 * bflo(v2.w); acc[i][7] += w2 * bfhi(v2.w);
                    acc[i][0] += w3 * bflo(v3.x); acc[i][1] += w3 * bfhi(v3.x);
                    acc[i][2] += w3 * bflo(v3.y); acc[i][3] += w3 * bfhi(v3.y);
                    acc[i][4] += w3 * bflo(v3.z); acc[i][5] += w3 * bfhi(v3.z);
                    acc[i][6] += w3 * bflo(v3.w); acc[i][7] += w3 * bfhi(v3.w);
                }
            }
        }
    };
    if (nE <= ADJ_CAP) gather([&](int o) { return ldsAdj[o]; });
    else               gather([&](int o) { return p.adj[est + o]; });

    // write agg tile (bf16, 16-slot swizzle), 256B/row
#pragma unroll
    for (int i = 0; i < 4; ++i) {
        int lr = grp * 4 + i;
        uint4 o = make_uint4(pack2(acc[i][0], acc[i][1]), pack2(acc[i][2], acc[i][3]),
                             pack2(acc[i][4], acc[i][5]), pack2(acc[i][6], acc[i][7]));
        int colb = l * 16;
        *(uint4*)(lds + lr * 256 + (colb ^ ((lr & 15) << 4))) = o;
    }
    __syncthreads();

    // MFMA phase: 32x32x16, wave = col-tile; ks outer (B loaded once), 2 row-tiles inner
    const int wave = tid >> 6;
    const int lane = tid & 63;
    const int l5 = lane >> 5;
    const int l31 = lane & 31;
    const short* bp = p.Bpack + (size_t)wave * KS * 64 * 8;

    f32x16 acc0 = {0.f, 0.f, 0.f, 0.f, 0.f, 0.f, 0.f, 0.f, 0.f, 0.f, 0.f, 0.f, 0.f, 0.f, 0.f, 0.f};
    f32x16 acc1 = acc0;

    int sr0 = node0 + l31;      if (sr0 >= p.M) sr0 = p.M - 1;
    int sr1 = node0 + 32 + l31; if (sr1 >= p.M) sr1 = p.M - 1;
    const int r0 = l31, r1 = 32 + l31;

#pragma unroll
    for (int ks = 0; ks < KS; ++ks) {
        short8 bf = *(const short8*)(bp + ((size_t)ks * 64 + lane) * 8);
        short8 a0, a1;
        if (ks < 8) {
            int colb = ks * 32 + l5 * 16;
            a0 = *(const short8*)(lds + r0 * 256 + (colb ^ ((r0 & 15) << 4)));
            a1 = *(const short8*)(lds + r1 * 256 + (colb ^ ((r1 & 15) << 4)));
        } else {
            int off = (ks - 8) * 16 + l5 * 8;
            a0 = *(const short8*)(p.selfx + (size_t)sr0 * DD + off);
            a1 = *(const short8*)(p.selfx + (size_t)sr1 * DD + off);
        }
        acc0 = __builtin_amdgcn_mfma_f32_32x32x16_bf16(a0, bf, acc0, 0, 0, 0);
        acc1 = __builtin_amdgcn_mfma_f32_32x32x16_bf16(a1, bf, acc1, 0, 0, 0);
    }

    // epilogue: C layout col=lane&31, row=(g&3)+8*(g>>2)+4*(lane>>5)
    const int col = wave * 32 + l31;
    const float bb = p.b1[col];
    const float b2v = HAS_B2 ? p.b2[col] : 0.f;
    {
        int rb = node0 + 4 * l5;
#pragma unroll
        for (int g = 0; g < 16; ++g) {
            int row = rb + (g & 3) + 8 * (g >> 2);
            if (row < p.M) {
                float v = acc0[g] + (float)p.cnt[row] * bb + b2v;
                if (ADD_BASE) v += bf2f(p.base[(size_t)row * DD + col]);
                p.out[(size_t)row * DD + col] = f2bf(v);
            }
        }
        rb += 32;
#pragma unroll
        for (int g = 0; g < 16; ++g) {
            int row = rb + (g & 3) + 8 * (g >> 2);
            if (row < p.M) {
                float v = acc1[g] + (float)p.cnt[row] * bb + b2v;
                if (ADD_BASE) v += bf2f(p.base[(size_t)row * DD + col]);
                p.out[(size_t)row * DD + col] = f2bf(v);
            }
        }
    }
}

__global__ __launch_bounds__(256, 5) void fused_dual_kernel(FParams pP, FParams pA, int blkP) {
    __shared__ char lds[16384];
    __shared__ int ldsAdj[ADJ_CAP];
    bool isP = (int)blockIdx.x < blkP;
    const FParams& p = isP ? pP : pA;
    fused_body<16, true, false>(lds, ldsAdj, p, isP ? blockIdx.x : blockIdx.x - blkP);
}

__global__ __launch_bounds__(256, 5) void fused_co_kernel(FParams p) {
    __shared__ char lds[16384];
    __shared__ int ldsAdj[ADJ_CAP];
    fused_body<8, false, true>(lds, ldsAdj, p, blockIdx.x);
}

// ---------------- supervision dot ----------------
__global__ __launch_bounds__(256) void dot_kernel(
    const unsigned short* __restrict__ xa, const unsigned short* __restrict__ xp,
    const int* __restrict__ s0, const int* __restrict__ s1,
    float* __restrict__ out, int E) {
    int g = blockIdx.x * blockDim.x + threadIdx.x;
    int e = g >> 4;
    int l = g & 15;
    if (e >= E) return;
    int a = s0[e], p = s1[e];
    uint4 va = *(const uint4*)(xa + (size_t)a * DD + l * 8);
    uint4 vp = *(const uint4*)(xp + (size_t)p * DD + l * 8);
    float s = bflo(va.x) * bflo(vp.x) + bfhi(va.x) * bfhi(vp.x)
            + bflo(va.y) * bflo(vp.y) + bfhi(va.y) * bfhi(vp.y)
            + bflo(va.z) * bflo(vp.z) + bfhi(va.z) * bfhi(vp.z)
            + bflo(va.w) * bflo(vp.w) + bfhi(va.w) * bfhi(vp.w);
    s += __shfl_xor(s, 1); s += __shfl_xor(s, 2);
    s += __shfl_xor(s, 4); s += __shfl_xor(s, 8);
    if (l == 0) out[e] = s;
}

extern "C" void kernel_launch(void* const* d_in, const int* in_sizes, int n_in,
                              void* d_out, int out_size, void* d_ws, size_t ws_size,
                              hipStream_t stream) {
    const float* xa_in = (const float*)d_in[0];
    const float* xp_in = (const float*)d_in[1];
    const int* eidx = (const int*)d_in[2];
    const int* co = (const int*)d_in[3];
    const int* sup = (const int*)d_in[4];
    const float* W_a2p = (const float*)d_in[5];
    const float* b_a2p = (const float*)d_in[6];
    const float* W_p2a = (const float*)d_in[7];
    const float* b_p2a = (const float*)d_in[8];
    const float* W_aself = (const float*)d_in[9];
    const float* b_aself = (const float*)d_in[10];
    const float* W_pself = (const float*)d_in[11];
    const float* b_pself = (const float*)d_in[12];
    const float* W_co = (const float*)d_in[13];
    const float* b_co = (const float*)d_in[14];

    const int NA = in_sizes[0] / DD;
    const int NP = in_sizes[1] / DD;
    const int E = in_sizes[2] / 2;
    const int Eco = in_sizes[3] / 2;
    const int Esup = in_sizes[4] / 2;
    const int* a_idx = eidx;
    const int* p_idx = eidx + E;
    const int* co_s = co;
    const int* co_d = co + Eco;
    const int* s0 = sup;
    const int* s1 = sup + Esup;

    char* w = (char*)d_ws;
    auto carve = [&](size_t bytes) -> char* {
        char* p = w;
        w += (bytes + 255) & ~(size_t)255;
        return p;
    };
    unsigned short* XA = (unsigned short*)carve((size_t)NA * DD * 2);
    unsigned short* XP = (unsigned short*)carve((size_t)NP * DD * 2);
    unsigned short* P0b = (unsigned short*)carve((size_t)NP * DD * 2);
    unsigned short* P1b = (unsigned short*)carve((size_t)NP * DD * 2);
    unsigned short* A0b = (unsigned short*)carve((size_t)NA * DD * 2);
    unsigned short* A1b = (unsigned short*)carve((size_t)NA * DD * 2);
    int* cntP = (int*)carve((size_t)NP * 4);
    int* cntA = (int*)carve((size_t)NA * 4);
    int* cntC = (int*)carve((size_t)NA * 4);
    size_t cntSpan = (size_t)((char*)cntC - (char*)cntP) + (((size_t)NA * 4 + 255) & ~(size_t)255);
    int* rowP = (int*)carve((size_t)NP * 4);
    int* curP = (int*)carve((size_t)NP * 4);
    int* rowA = (int*)carve((size_t)NA * 4);
    int* curA = (int*)carve((size_t)NA * 4);
    int* rowC = (int*)carve((size_t)NA * 4);
    int* curC = (int*)carve((size_t)NA * 4);
    int* adjP = (int*)carve((size_t)E * 4);
    int* adjA = (int*)carve((size_t)E * 4);
    int* adjC = (int*)carve((size_t)Eco * 4);
    int* partP = (int*)carve(256 * 4);
    int* partA = (int*)carve(256 * 4);
    int* partC = (int*)carve(256 * 4);
    short* BPp0 = (short*)carve(4 * 16 * 64 * 8 * 2);
    short* BPp1 = (short*)carve(4 * 16 * 64 * 8 * 2);
    short* BPa0 = (short*)carve(4 * 16 * 64 * 8 * 2);
    short* BPa1 = (short*)carve(4 * 16 * 64 * 8 * 2);
    short* BPc0 = (short*)carve(4 * 8 * 64 * 8 * 2);
    short* BPc1 = (short*)carve(4 * 8 * 64 * 8 * 2);

    int n4A = NA * DD / 4, n4P = NP * DD / 4;
    conv_all<<<(n4A + n4P + 255) / 256, 256, 0, stream>>>(xa_in, XA, n4A, xp_in, XP, n4P);
    pack_all<<<96, 256, 0, stream>>>(W_a2p, W_pself, W_p2a, W_aself, W_co, BPp0, BPp1, BPa0, BPa1, BPc0, BPc1);

    hipMemsetAsync(cntP, 0, cntSpan, stream);
    count_all<<<(E + Eco + 255) / 256, 256, 0, stream>>>(a_idx, p_idx, co_d, cntP, cntA, cntC, E, Eco);
    const int nbP = (NP + 1023) / 1024;
    const int nbA = (NA + 1023) / 1024;
    scan_local3<<<nbP + nbA + nbA, 256, 0, stream>>>(cntP, rowP, partP, NP, cntA, rowA, partA, NA, cntC, rowC, partC, NA, nbP, nbA);
    scan_partials3<<<3, 256, 0, stream>>>(partP, nbP, partA, nbA, partC, nbA);
    const int fbP = (NP + 255) / 256;
    const int fbA = (NA + 255) / 256;
    scan_finalize3<<<fbP + fbA + fbA, 256, 0, stream>>>(rowP, curP, partP, NP, rowA, curA, partA, NA, rowC, curC, partC, NA, fbP, fbA);
    fill_all<<<(E + Eco + 255) / 256, 256, 0, stream>>>(a_idx, p_idx, co_s, co_d, curP, curA, curC, adjP, adjA, adjC, E, Eco);

    const int blkP = (NP + 63) / 64;
    const int blkA = (NA + 63) / 64;

    FParams pP1 = {XA, XP, nullptr, adjP, rowP, cntP, BPp0, b_a2p, b_pself, P0b, NP};
    FParams pA1 = {XP, XA, nullptr, adjA, rowA, cntA, BPa0, b_p2a, b_aself, A0b, NA};
    FParams pC1 = {A0b, nullptr, A0b, adjC, rowC, cntC, BPc0, b_co, nullptr, A1b, NA};
    FParams pP2 = {A1b, P0b, nullptr, adjP, rowP, cntP, BPp1, b_a2p + 128, b_pself + 128, P1b, NP};
    FParams pA2 = {P0b, A1b, nullptr, adjA, rowA, cntA, BPa1, b_p2a + 128, b_aself + 128, A0b, NA};
    FParams pC2 = {A0b, nullptr, A0b, adjC, rowC, cntC, BPc1, b_co + 128, nullptr, A1b, NA};

    // Layer 1
    fused_dual_kernel<<<blkP + blkA, 256, 0, stream>>>(pP1, pA1, blkP);
    fused_co_kernel<<<blkA, 256, 0, stream>>>(pC1);
    // Layer 2
    fused_dual_kernel<<<blkP + blkA, 256, 0, stream>>>(pP2, pA2, blkP);
    fused_co_kernel<<<blkA, 256, 0, stream>>>(pC2);

    // output
    dot_kernel<<<(Esup * 16 + 255) / 256, 256, 0, stream>>>(A1b, P1b, s0, s1, (float*)d_out, Esup);
}